// Round 15
// baseline (116.259 us; speedup 1.0000x reference)
//
#include <hip/hip_runtime.h>
#include <hip/hip_bf16.h>

#define NEG 0.2f
#define BSTRIDE 8192   // padded per-bucket region (mean fill ~4350, 60-sigma headroom)

typedef float vf4 __attribute__((ext_vector_type(4)));
typedef int   vi4 __attribute__((ext_vector_type(4)));
typedef short bf8 __attribute__((ext_vector_type(8)));   // 8 bf16 (4 VGPRs)
typedef float f32x4 __attribute__((ext_vector_type(4)));

__device__ __forceinline__ float leaky(float x){ return x > 0.f ? x : NEG*x; }
__device__ __forceinline__ float sel4(float4 q, int head){
  float lo = (head & 1) ? q.y : q.x;
  float hi = (head & 1) ? q.w : q.z;
  return (head & 2) ? hi : lo;
}
__device__ __forceinline__ float b2f_lo(unsigned u){ return __uint_as_float(u << 16); }
__device__ __forceinline__ float b2f_hi(unsigned u){ return __uint_as_float(u & 0xffff0000u); }
__device__ __forceinline__ float b2f(unsigned short u){ return __uint_as_float((unsigned)u << 16); }
__device__ __forceinline__ unsigned short f2b(float f){
  __hip_bfloat16 b = __float2bfloat16(f);
  return *(unsigned short*)&b;
}
__device__ __forceinline__ vi4 ntload_i4(const int* p){
  return __builtin_nontemporal_load((const vi4*)p);
}
__device__ __forceinline__ void ntstore_f4(float* p, float a, float b, float c, float d){
  vf4 v; v.x = a; v.y = b; v.z = c; v.w = d;
  __builtin_nontemporal_store(v, (vf4*)p);
}

// ---------------- K0: fcw -> bf16 (row-major, 32KB -> L1-resident); seeds bcur ----
__global__ __launch_bounds__(256) void k_wconv(const float* __restrict__ fcw,
    unsigned short* __restrict__ fcw16, int* __restrict__ bcur) {
  const int tid = threadIdx.x;
  if (blockIdx.x == 0) bcur[tid] = tid * BSTRIDE;
  const int i = (blockIdx.x*256 + tid) * 8;      // 8 blocks x 256 x 8 = 16384
  float4 w0 = *(const float4*)&fcw[i];
  float4 w1 = *(const float4*)&fcw[i + 4];
  unsigned short q[8];
  q[0]=f2b(w0.x); q[1]=f2b(w0.y); q[2]=f2b(w0.z); q[3]=f2b(w0.w);
  q[4]=f2b(w1.x); q[5]=f2b(w1.y); q[6]=f2b(w1.z); q[7]=f2b(w1.w);
  *(uint4*)&fcw16[i] = *(const uint4*)q;
}

// ---------------- K1: hf16 = bf16(h @ fcw16^T) via MFMA, fused el/er ----------------
// B-frags read directly from global fcw16 (32KB, L1-resident). LDS = D staging only.
__global__ __launch_bounds__(256) void k_proj(
    const float* __restrict__ h, const unsigned short* __restrict__ fcw16,
    const float* __restrict__ attn_l, const float* __restrict__ attn_r,
    unsigned short* __restrict__ hf16, float* __restrict__ el, float* __restrict__ er, int N)
{
  __shared__ __align__(16) unsigned short hs[4][16*128];  // 16 KB D staging

  const int tid = threadIdx.x;
  const int wave = tid >> 6, lane = tid & 63;
  const int r = lane & 15, khi = lane >> 4;      // A row / B col ; k-group 0..3
  const int nb0 = blockIdx.x*64 + wave*16;
  int gn_a = nb0 + r; if (gn_a >= N) gn_a = N-1;
  const float* hp = &h[(size_t)gn_a*128];

  // A-frags: k = ks*32 + khi*8 + j (matches B's k layout)
  bf8 afr[4];
  #pragma unroll
  for (int ks = 0; ks < 4; ++ks) {
    const float* p = hp + ks*32 + khi*8;
    float4 w0 = *(const float4*)p;
    float4 w1 = *(const float4*)(p + 4);
    bf8 a;
    a[0]=(short)f2b(w0.x); a[1]=(short)f2b(w0.y); a[2]=(short)f2b(w0.z); a[3]=(short)f2b(w0.w);
    a[4]=(short)f2b(w1.x); a[5]=(short)f2b(w1.y); a[6]=(short)f2b(w1.z); a[7]=(short)f2b(w1.w);
    afr[ks] = a;
  }

  f32x4 acc[8];
  #pragma unroll
  for (int ct = 0; ct < 8; ++ct) { acc[ct][0]=0.f; acc[ct][1]=0.f; acc[ct][2]=0.f; acc[ct][3]=0.f; }

  #pragma unroll
  for (int ct = 0; ct < 8; ++ct) {
    const int f = ct*16 + r;                     // B col = feat
    #pragma unroll
    for (int ks = 0; ks < 4; ++ks) {
      bf8 b = *(const bf8*)&fcw16[(size_t)f*128 + ks*32 + khi*8];   // L1 hit
      acc[ct] = __builtin_amdgcn_mfma_f32_16x16x32_bf16(afr[ks], b, acc[ct], 0, 0, 0);
    }
  }

  // D -> LDS (bf16). D map: col=lane&15 (feat), row=khi*4+j (node)
  unsigned short* hw = &hs[wave][0];
  #pragma unroll
  for (int ct = 0; ct < 8; ++ct) {
    const int ftile = ct*16 + r;
    #pragma unroll
    for (int j = 0; j < 4; ++j)
      hw[(khi*4 + j)*128 + ftile] = f2b(acc[ct][j]);
  }

  // coalesced hf16 writeback (wave-local LDS, no barrier needed)
  for (int i = lane; i < 16*16; i += 64) {
    int row = i >> 4, ch = i & 15;
    int gn = nb0 + row;
    if (gn < N)
      *(uint4*)&hf16[(size_t)gn*128 + ch*8] = *(const uint4*)&hw[row*128 + ch*8];
  }

  // el/er: lane = (node row, head); 32-MAC dot from LDS tile
  {
    const int row = lane >> 2, head = lane & 3;
    const int gn = nb0 + row;
    const unsigned short* hr = &hw[row*128 + head*32];
    const float* alp = &attn_l[head*32];
    const float* arp = &attn_r[head*32];
    float e_l = 0.f, e_r = 0.f;
    #pragma unroll
    for (int ff = 0; ff < 32; ++ff) {
      float hv = b2f(hr[ff]);
      e_l += hv * alp[ff];
      e_r += hv * arp[ff];
    }
    if (gn < N) {
      el[(size_t)gn*4 + head] = e_l;
      er[(size_t)gn*4 + head] = e_r;
    }
  }
}

// ---------------- pass 1: bin edges into padded bucket regions ----------------
// staging word: (dst&255)<<24 | src   (src < 2^24)
#define TILE 4096
__global__ __launch_bounds__(1024) void k_bin(
    const int* __restrict__ src, const int* __restrict__ dst,
    int* __restrict__ bcur, unsigned int* __restrict__ staging, int E)
{
  __shared__ unsigned int lpack[TILE];
  __shared__ unsigned char lbkt[TILE];
  __shared__ unsigned short sidx[TILE];
  __shared__ int lhist[256], lbase[256], lcur[256], gbase[256];

  const int t = threadIdx.x;
  const int e0 = blockIdx.x * TILE;
  const int cnt = min(TILE, E - e0);

  if (t < 256) lhist[t] = 0;
  __syncthreads();

  for (int i = t; i < cnt; i += 1024) {
    int s = __builtin_nontemporal_load(&src[e0 + i]);
    int d = __builtin_nontemporal_load(&dst[e0 + i]);
    lpack[i] = ((unsigned)(d & 255) << 24) | (unsigned)s;
    int b = d >> 8;
    lbkt[i] = (unsigned char)b;
    atomicAdd(&lhist[b], 1);
  }
  __syncthreads();

  __shared__ int ltmp[256];
  if (t < 256) ltmp[t] = lhist[t];
  __syncthreads();
  for (int off = 1; off < 256; off <<= 1) {
    int x = 0;
    if (t < 256 && t >= off) x = ltmp[t - off];
    __syncthreads();
    if (t < 256) ltmp[t] += x;
    __syncthreads();
  }
  if (t < 256) { lbase[t] = ltmp[t] - lhist[t]; lcur[t] = ltmp[t] - lhist[t]; }
  __syncthreads();

  for (int i = t; i < cnt; i += 1024) {
    int p = atomicAdd(&lcur[lbkt[i]], 1);
    sidx[p] = (unsigned short)i;
  }
  if (t < 256) {
    int c = lhist[t];
    gbase[t] = c ? atomicAdd(&bcur[t], c) : 0;
  }
  __syncthreads();

  for (int p = t; p < cnt; p += 1024) {
    int j = sidx[p];
    int b = lbkt[j];
    staging[gbase[b] + (p - lbase[b])] = lpack[j];
  }
}

// ---------------- pass 2: per-bucket counting sort -> padded esrc + offsets/degs ----
__global__ __launch_bounds__(1024) void k_debin(
    const unsigned int* __restrict__ staging, const int* __restrict__ bcur,
    int* __restrict__ esrc, int* __restrict__ offsets, int* __restrict__ degs, int N)
{
  __shared__ int lout[BSTRIDE];
  __shared__ int lhist[256], lexcl[256], lcur[256];

  const int t = threadIdx.x;
  const int b = blockIdx.x;
  const int n0 = b << 8;
  const int nb = min(256, N - n0);
  const int out_start = b * BSTRIDE;
  const int cnt = bcur[b] - out_start;

  if (t < 256) lhist[t] = 0;
  __syncthreads();

  for (int i = t; i < cnt; i += 1024)
    atomicAdd(&lhist[staging[out_start + i] >> 24], 1);
  __syncthreads();

  if (t < 256) lexcl[t] = lhist[t];
  __syncthreads();
  for (int off = 1; off < 256; off <<= 1) {
    int x = 0;
    if (t < 256 && t >= off) x = lexcl[t - off];
    __syncthreads();
    if (t < 256) lexcl[t] += x;
    __syncthreads();
  }
  if (t < 256) {
    int ex = lexcl[t] - lhist[t];
    lexcl[t] = ex;
    lcur[t]  = ex;
  }
  __syncthreads();

  for (int i = t; i < cnt; i += 1024) {
    unsigned int w = staging[out_start + i];
    int p = atomicAdd(&lcur[w >> 24], 1);
    lout[p] = (int)(w & 0x00FFFFFFu);
  }
  __syncthreads();
  for (int i = t; i < cnt; i += 1024)
    esrc[out_start + i] = lout[i];

  if (t < nb) {
    offsets[n0 + t] = out_start + lexcl[t];
    degs[n0 + t]    = lhist[t];
  }
}

// ---------------- K2: per-dst softmax + aggregation (1 wave per node) ----------------
// Softmax WITHOUT max-shift: scores bounded, fp32 exp safe, shift-invariant.
// pass B: 8 edge groups x 8 lanes, acc[16], 2-deep pipeline (measured best).
__global__ __launch_bounds__(256) void k_aggr(
    const int* __restrict__ esrc, const int* __restrict__ offsets, const int* __restrict__ degs,
    const unsigned short* __restrict__ hf16, const float* __restrict__ el, const float* __restrict__ er,
    float* __restrict__ out, float* __restrict__ mr, int N)
{
  __shared__ float as[4][64][4];
  __shared__ int   es[4][64];
  const int wave = threadIdx.x >> 6, lane = threadIdx.x & 63;
  const int v = blockIdx.x*4 + wave;
  if (v >= N) return;
  const int start = offsets[v];
  const int deg   = degs[v];
  const float4 er4 = *(const float4*)&er[(size_t)v*4];

  const bool act = lane < deg;
  float4 x4 = make_float4(0.f, 0.f, 0.f, 0.f);
  int mys = 0;
  if (act) {
    mys = esrc[start + lane];
    float4 el4 = *(const float4*)&el[(size_t)mys*4];
    x4.x = __expf(leaky(el4.x + er4.x));
    x4.y = __expf(leaky(el4.y + er4.y));
    x4.z = __expf(leaky(el4.z + er4.z));
    x4.w = __expf(leaky(el4.w + er4.w));
  }
  float4 s4 = x4;
  for (int j = lane + 64; j < deg; j += 64) {   // deg>64: essentially never
    int s = esrc[start + j];
    float4 el4 = *(const float4*)&el[(size_t)s*4];
    s4.x += __expf(leaky(el4.x + er4.x));
    s4.y += __expf(leaky(el4.y + er4.y));
    s4.z += __expf(leaky(el4.z + er4.z));
    s4.w += __expf(leaky(el4.w + er4.w));
  }
  #pragma unroll
  for (int mm = 32; mm; mm >>= 1) {
    s4.x += __shfl_xor(s4.x, mm);
    s4.y += __shfl_xor(s4.y, mm);
    s4.z += __shfl_xor(s4.z, mm);
    s4.w += __shfl_xor(s4.w, mm);
  }
  const float4 r4 = make_float4(1.f/s4.x, 1.f/s4.y, 1.f/s4.z, 1.f/s4.w);

  if (act) {
    float4 a4 = make_float4(x4.x*r4.x, x4.y*r4.y, x4.z*r4.z, x4.w*r4.w);
    *(float4*)&as[wave][lane][0] = a4;
    es[wave][lane] = mys;
  }
  if (lane == 0) *(float4*)&mr[(size_t)v*4] = r4;   // c = r (no max shift)

  // ---- pass B: aggregate, 8 groups x 8 lanes, 2-deep pipelined (16 edges in flight) ----
  const int g = lane >> 3;      // edge slot 0..7
  const int l = lane & 7;       // feature sublane: feats 16l..16l+15
  const int head = l >> 1;
  float acc[16];
  #pragma unroll
  for (int k = 0; k < 16; ++k) acc[k] = 0.f;

  const int degL = deg < 64 ? deg : 64;
  {
    int je = g;
    int jec = je < degL ? je : 0;
    int sj = es[wave][jec];
    float a = je < degL ? as[wave][jec][head] : 0.f;
    const unsigned short* hp = &hf16[(size_t)sj*128 + 16*l];
    uint4 q0 = *(const uint4*)hp;
    uint4 q1 = *(const uint4*)(hp + 8);
    for (int j = 0; j < degL; j += 8) {
      int je2 = j + 8 + g;
      int jec2 = je2 < degL ? je2 : 0;
      int s2 = es[wave][jec2];
      float a2 = je2 < degL ? as[wave][jec2][head] : 0.f;
      const unsigned short* hp2 = &hf16[(size_t)s2*128 + 16*l];
      uint4 p0 = *(const uint4*)hp2;
      uint4 p1 = *(const uint4*)(hp2 + 8);
      acc[0]  += a*b2f_lo(q0.x); acc[1]  += a*b2f_hi(q0.x);
      acc[2]  += a*b2f_lo(q0.y); acc[3]  += a*b2f_hi(q0.y);
      acc[4]  += a*b2f_lo(q0.z); acc[5]  += a*b2f_hi(q0.z);
      acc[6]  += a*b2f_lo(q0.w); acc[7]  += a*b2f_hi(q0.w);
      acc[8]  += a*b2f_lo(q1.x); acc[9]  += a*b2f_hi(q1.x);
      acc[10] += a*b2f_lo(q1.y); acc[11] += a*b2f_hi(q1.y);
      acc[12] += a*b2f_lo(q1.z); acc[13] += a*b2f_hi(q1.z);
      acc[14] += a*b2f_lo(q1.w); acc[15] += a*b2f_hi(q1.w);
      q0 = p0; q1 = p1; a = a2;
    }
  }
  for (int j = 64; j < deg; j += 8) {   // deg>64: essentially never
    const int je = j + g;
    const bool valid = je < deg;
    int s = esrc[start + (valid ? je : 0)];
    float rh = sel4(r4, head), erh = sel4(er4, head);
    float a = __expf(leaky(el[(size_t)s*4 + head] + erh)) * rh;
    if (!valid) a = 0.f;
    const unsigned short* hp = &hf16[(size_t)s*128 + 16*l];
    uint4 q0 = *(const uint4*)hp;
    uint4 q1 = *(const uint4*)(hp + 8);
    acc[0]  += a*b2f_lo(q0.x); acc[1]  += a*b2f_hi(q0.x);
    acc[2]  += a*b2f_lo(q0.y); acc[3]  += a*b2f_hi(q0.y);
    acc[4]  += a*b2f_lo(q0.z); acc[5]  += a*b2f_hi(q0.z);
    acc[6]  += a*b2f_lo(q0.w); acc[7]  += a*b2f_hi(q0.w);
    acc[8]  += a*b2f_lo(q1.x); acc[9]  += a*b2f_hi(q1.x);
    acc[10] += a*b2f_lo(q1.y); acc[11] += a*b2f_hi(q1.y);
    acc[12] += a*b2f_lo(q1.z); acc[13] += a*b2f_hi(q1.z);
    acc[14] += a*b2f_lo(q1.w); acc[15] += a*b2f_hi(q1.w);
  }

  #pragma unroll
  for (int k = 0; k < 16; ++k) {
    acc[k] += __shfl_xor(acc[k], 8);
    acc[k] += __shfl_xor(acc[k], 16);
    acc[k] += __shfl_xor(acc[k], 32);
  }
  if (g == 0) {
    float* op = &out[(size_t)v*128 + 16*l];
    ntstore_f4(op,      acc[0],  acc[1],  acc[2],  acc[3]);
    ntstore_f4(op + 4,  acc[4],  acc[5],  acc[6],  acc[7]);
    ntstore_f4(op + 8,  acc[8],  acc[9],  acc[10], acc[11]);
    ntstore_f4(op + 12, acc[12], acc[13], acc[14], acc[15]);
  }
}

// ---------------- K3: coalesced attention output, 4 edges/thread ----------------
// a = exp(leaky(el+er)) * c   with c = 1/sum(exp)  (no max shift)
__global__ void k_attn(const int* __restrict__ src, const int* __restrict__ dst,
                       const float* __restrict__ el, const float* __restrict__ er,
                       const float* __restrict__ mr, float* __restrict__ a_out, int E) {
  int e0 = (blockIdx.x*256 + threadIdx.x)*4;
  if (e0 + 3 < E) {
    vi4 sv = ntload_i4(&src[e0]);
    vi4 dv = ntload_i4(&dst[e0]);
    #pragma unroll
    for (int k = 0; k < 4; ++k) {
      int s = (k==0)?sv.x:(k==1)?sv.y:(k==2)?sv.z:sv.w;
      int d = (k==0)?dv.x:(k==1)?dv.y:(k==2)?dv.z:dv.w;
      float4 el4 = *(const float4*)&el[(size_t)s*4];
      float4 er4 = *(const float4*)&er[(size_t)d*4];
      float4 c4  = *(const float4*)&mr[(size_t)d*4];
      ntstore_f4(&a_out[(size_t)(e0+k)*4],
                 __expf(leaky(el4.x + er4.x)) * c4.x,
                 __expf(leaky(el4.y + er4.y)) * c4.y,
                 __expf(leaky(el4.z + er4.z)) * c4.z,
                 __expf(leaky(el4.w + er4.w)) * c4.w);
    }
  } else {
    for (int e = e0; e < E; ++e) {
      int s = src[e], d = dst[e];
      float4 el4 = *(const float4*)&el[(size_t)s*4];
      float4 er4 = *(const float4*)&er[(size_t)d*4];
      float4 c4  = *(const float4*)&mr[(size_t)d*4];
      ntstore_f4(&a_out[(size_t)e*4],
                 __expf(leaky(el4.x + er4.x)) * c4.x,
                 __expf(leaky(el4.y + er4.y)) * c4.y,
                 __expf(leaky(el4.z + er4.z)) * c4.z,
                 __expf(leaky(el4.w + er4.w)) * c4.w);
    }
  }
}

extern "C" void kernel_launch(void* const* d_in, const int* in_sizes, int n_in,
                              void* d_out, int out_size, void* d_ws, size_t ws_size,
                              hipStream_t stream) {
  const float* h      = (const float*)d_in[0];
  const float* fcw    = (const float*)d_in[1];
  const float* attn_l = (const float*)d_in[2];
  const float* attn_r = (const float*)d_in[3];
  const int*   src    = (const int*)d_in[4];
  const int*   dst    = (const int*)d_in[5];
  const int N = in_sizes[0] / 128;
  const int E = in_sizes[4];
  const int B = (N + 255) >> 8;    // buckets (assumes N <= 65536)

  float* out   = (float*)d_out;
  float* a_out = out + (size_t)N*128;

  char* w = (char*)d_ws;
  unsigned short* hf16 = (unsigned short*)w; w += (size_t)N*128*sizeof(unsigned short);
  unsigned short* fcw16 = (unsigned short*)w; w += (size_t)128*128*sizeof(unsigned short);
  float* el      = (float*)w; w += (size_t)N*4*sizeof(float);
  float* er      = (float*)w; w += (size_t)N*4*sizeof(float);
  float* mr      = (float*)w; w += (size_t)N*4*sizeof(float);
  int*   esrc    = (int*)w;   w += (size_t)256*BSTRIDE*sizeof(int);
  unsigned int* staging = (unsigned int*)w; w += (size_t)256*BSTRIDE*sizeof(unsigned int);
  int*   offsets = (int*)w;   w += (size_t)N*sizeof(int);
  int*   degs    = (int*)w;   w += (size_t)N*sizeof(int);
  int*   bcur    = (int*)w;   w += 256*sizeof(int);

  k_wconv<<<8, 256, 0, stream>>>(fcw, fcw16, bcur);

  k_proj<<<(N + 63)/64, 256, 0, stream>>>(h, fcw16, attn_l, attn_r, hf16, el, er, N);

  k_bin<<<(E + TILE - 1)/TILE, 1024, 0, stream>>>(src, dst, bcur, staging, E);
  k_debin<<<B, 1024, 0, stream>>>(staging, bcur, esrc, offsets, degs, N);

  k_aggr<<<(N + 3)/4, 256, 0, stream>>>(esrc, offsets, degs, hf16, el, er, out, mr, N);

  k_attn<<<(E/4 + 255)/256 + 1, 256, 0, stream>>>(src, dst, el, er, mr, a_out, E);
}

// Round 16
// 106.997 us; speedup vs baseline: 1.0866x; 1.0866x over previous
//
#include <hip/hip_runtime.h>
#include <hip/hip_bf16.h>

#define NEG 0.2f
#define BSTRIDE 8192   // padded per-bucket region (mean fill ~4350, 60-sigma headroom)

typedef float vf4 __attribute__((ext_vector_type(4)));
typedef int   vi4 __attribute__((ext_vector_type(4)));
typedef short bf8 __attribute__((ext_vector_type(8)));   // 8 bf16 (4 VGPRs)
typedef float f32x4 __attribute__((ext_vector_type(4)));

__device__ __forceinline__ float leaky(float x){ return x > 0.f ? x : NEG*x; }
__device__ __forceinline__ float sel4(float4 q, int head){
  float lo = (head & 1) ? q.y : q.x;
  float hi = (head & 1) ? q.w : q.z;
  return (head & 2) ? hi : lo;
}
__device__ __forceinline__ float b2f_lo(unsigned u){ return __uint_as_float(u << 16); }
__device__ __forceinline__ float b2f_hi(unsigned u){ return __uint_as_float(u & 0xffff0000u); }
__device__ __forceinline__ float b2f(unsigned short u){ return __uint_as_float((unsigned)u << 16); }
__device__ __forceinline__ unsigned short f2b(float f){
  __hip_bfloat16 b = __float2bfloat16(f);
  return *(unsigned short*)&b;
}
__device__ __forceinline__ vi4 ntload_i4(const int* p){
  return __builtin_nontemporal_load((const vi4*)p);
}
__device__ __forceinline__ void ntstore_f4(float* p, float a, float b, float c, float d){
  vf4 v; v.x = a; v.y = b; v.z = c; v.w = d;
  __builtin_nontemporal_store(v, (vf4*)p);
}

// ---------------- K1: hf16 = bf16(h @ fcw^T) via MFMA, fused el/er ----------------
// 128 nodes/block (2 node-tiles per wave over one fcw LDS staging). Block 0 seeds bcur.
// (Round-15 lesson: B-frags from global/L1 regressed -11us; LDS is the right home.)
__global__ __launch_bounds__(256) void k_proj(
    const float* __restrict__ h, const float* __restrict__ fcw,
    const float* __restrict__ attn_l, const float* __restrict__ attn_r,
    unsigned short* __restrict__ hf16, float* __restrict__ el, float* __restrict__ er,
    int* __restrict__ bcur, int N)
{
  __shared__ __align__(16) unsigned short fcs[128*128];   // 32 KB bf16, swizzled
  __shared__ __align__(16) unsigned short hs[4][16*128];  // 16 KB D staging

  const int tid = threadIdx.x;
  if (blockIdx.x == 0) bcur[tid] = tid * BSTRIDE;   // folded k_binit

  // stage fcw -> bf16 LDS; chunk (8 elems, 16B) swizzled by f&7
  for (int i = tid; i < 128*16; i += 256) {
    int f = i >> 4, ch = i & 15;
    const float* p = &fcw[(size_t)f*128 + ch*8];
    float4 w0 = *(const float4*)p;
    float4 w1 = *(const float4*)(p + 4);
    unsigned short* q = &fcs[f*128 + (ch ^ (f & 7))*8];
    q[0]=f2b(w0.x); q[1]=f2b(w0.y); q[2]=f2b(w0.z); q[3]=f2b(w0.w);
    q[4]=f2b(w1.x); q[5]=f2b(w1.y); q[6]=f2b(w1.z); q[7]=f2b(w1.w);
  }
  __syncthreads();

  const int wave = tid >> 6, lane = tid & 63;
  const int r = lane & 15, khi = lane >> 4;      // A row / B col ; k-group 0..3

  for (int nt = 0; nt < 2; ++nt) {
    const int nb0 = blockIdx.x*128 + nt*64 + wave*16;
    int gn_a = nb0 + r; if (gn_a >= N) gn_a = N-1;
    const float* hp = &h[(size_t)gn_a*128];

    // A-frags: k = ks*32 + khi*8 + j  (same k-permutation as B -> contraction invariant)
    bf8 afr[4];
    #pragma unroll
    for (int ks = 0; ks < 4; ++ks) {
      const float* p = hp + ks*32 + khi*8;
      float4 w0 = *(const float4*)p;
      float4 w1 = *(const float4*)(p + 4);
      bf8 a;
      a[0]=(short)f2b(w0.x); a[1]=(short)f2b(w0.y); a[2]=(short)f2b(w0.z); a[3]=(short)f2b(w0.w);
      a[4]=(short)f2b(w1.x); a[5]=(short)f2b(w1.y); a[6]=(short)f2b(w1.z); a[7]=(short)f2b(w1.w);
      afr[ks] = a;
    }

    f32x4 acc[8];
    #pragma unroll
    for (int ct = 0; ct < 8; ++ct) { acc[ct][0]=0.f; acc[ct][1]=0.f; acc[ct][2]=0.f; acc[ct][3]=0.f; }

    #pragma unroll
    for (int ct = 0; ct < 8; ++ct) {
      const int f = ct*16 + r;                   // B col = feat
      #pragma unroll
      for (int ks = 0; ks < 4; ++ks) {
        const int ch = (ks*4 + khi) ^ (f & 7);
        bf8 b = *(const bf8*)&fcs[f*128 + ch*8];
        acc[ct] = __builtin_amdgcn_mfma_f32_16x16x32_bf16(afr[ks], b, acc[ct], 0, 0, 0);
      }
    }

    // D -> LDS (bf16). D map: col=lane&15 (feat), row=khi*4+j (node)
    unsigned short* hw = &hs[wave][0];
    #pragma unroll
    for (int ct = 0; ct < 8; ++ct) {
      const int ftile = ct*16 + r;
      #pragma unroll
      for (int j = 0; j < 4; ++j)
        hw[(khi*4 + j)*128 + ftile] = f2b(acc[ct][j]);
    }

    // coalesced hf16 writeback (wave-local LDS, no barrier needed)
    for (int i = lane; i < 16*16; i += 64) {
      int row = i >> 4, ch = i & 15;
      int gn = nb0 + row;
      if (gn < N)
        *(uint4*)&hf16[(size_t)gn*128 + ch*8] = *(const uint4*)&hw[row*128 + ch*8];
    }

    // el/er: lane = (node row, head); 32-MAC dot from LDS tile
    {
      const int row = lane >> 2, head = lane & 3;
      const int gn = nb0 + row;
      const unsigned short* hr = &hw[row*128 + head*32];
      const float* alp = &attn_l[head*32];
      const float* arp = &attn_r[head*32];
      float e_l = 0.f, e_r = 0.f;
      #pragma unroll
      for (int ff = 0; ff < 32; ++ff) {
        float hv = b2f(hr[ff]);
        e_l += hv * alp[ff];
        e_r += hv * arp[ff];
      }
      if (gn < N) {
        el[(size_t)gn*4 + head] = e_l;
        er[(size_t)gn*4 + head] = e_r;
      }
    }
  }
}

// ---------------- pass 1: bin edges into padded bucket regions ----------------
// staging word: (dst&255)<<24 | src   (src < 2^24)
#define TILE 4096
__global__ __launch_bounds__(1024) void k_bin(
    const int* __restrict__ src, const int* __restrict__ dst,
    int* __restrict__ bcur, unsigned int* __restrict__ staging, int E)
{
  __shared__ unsigned int lpack[TILE];
  __shared__ unsigned char lbkt[TILE];
  __shared__ unsigned short sidx[TILE];
  __shared__ int lhist[256], lbase[256], lcur[256], gbase[256];

  const int t = threadIdx.x;
  const int e0 = blockIdx.x * TILE;
  const int cnt = min(TILE, E - e0);

  if (t < 256) lhist[t] = 0;
  __syncthreads();

  for (int i = t; i < cnt; i += 1024) {
    int s = __builtin_nontemporal_load(&src[e0 + i]);
    int d = __builtin_nontemporal_load(&dst[e0 + i]);
    lpack[i] = ((unsigned)(d & 255) << 24) | (unsigned)s;
    int b = d >> 8;
    lbkt[i] = (unsigned char)b;
    atomicAdd(&lhist[b], 1);
  }
  __syncthreads();

  __shared__ int ltmp[256];
  if (t < 256) ltmp[t] = lhist[t];
  __syncthreads();
  for (int off = 1; off < 256; off <<= 1) {
    int x = 0;
    if (t < 256 && t >= off) x = ltmp[t - off];
    __syncthreads();
    if (t < 256) ltmp[t] += x;
    __syncthreads();
  }
  if (t < 256) { lbase[t] = ltmp[t] - lhist[t]; lcur[t] = ltmp[t] - lhist[t]; }
  __syncthreads();

  for (int i = t; i < cnt; i += 1024) {
    int p = atomicAdd(&lcur[lbkt[i]], 1);
    sidx[p] = (unsigned short)i;
  }
  if (t < 256) {
    int c = lhist[t];
    gbase[t] = c ? atomicAdd(&bcur[t], c) : 0;
  }
  __syncthreads();

  for (int p = t; p < cnt; p += 1024) {
    int j = sidx[p];
    int b = lbkt[j];
    staging[gbase[b] + (p - lbase[b])] = lpack[j];
  }
}

// ---------------- pass 2: per-bucket counting sort -> padded esrc + offsets/degs ----
__global__ __launch_bounds__(1024) void k_debin(
    const unsigned int* __restrict__ staging, const int* __restrict__ bcur,
    int* __restrict__ esrc, int* __restrict__ offsets, int* __restrict__ degs, int N)
{
  __shared__ int lout[BSTRIDE];
  __shared__ int lhist[256], lexcl[256], lcur[256];

  const int t = threadIdx.x;
  const int b = blockIdx.x;
  const int n0 = b << 8;
  const int nb = min(256, N - n0);
  const int out_start = b * BSTRIDE;
  const int cnt = bcur[b] - out_start;

  if (t < 256) lhist[t] = 0;
  __syncthreads();

  for (int i = t; i < cnt; i += 1024)
    atomicAdd(&lhist[staging[out_start + i] >> 24], 1);
  __syncthreads();

  if (t < 256) lexcl[t] = lhist[t];
  __syncthreads();
  for (int off = 1; off < 256; off <<= 1) {
    int x = 0;
    if (t < 256 && t >= off) x = lexcl[t - off];
    __syncthreads();
    if (t < 256) lexcl[t] += x;
    __syncthreads();
  }
  if (t < 256) {
    int ex = lexcl[t] - lhist[t];
    lexcl[t] = ex;
    lcur[t]  = ex;
  }
  __syncthreads();

  for (int i = t; i < cnt; i += 1024) {
    unsigned int w = staging[out_start + i];
    int p = atomicAdd(&lcur[w >> 24], 1);
    lout[p] = (int)(w & 0x00FFFFFFu);
  }
  __syncthreads();
  for (int i = t; i < cnt; i += 1024)
    esrc[out_start + i] = lout[i];

  if (t < nb) {
    offsets[n0 + t] = out_start + lexcl[t];
    degs[n0 + t]    = lhist[t];
  }
}

// ---------------- K2: per-dst softmax + aggregation (1 wave per node) ----------------
// Softmax WITHOUT max-shift: scores bounded, fp32 exp safe, shift-invariant.
// pass B: 8 edge groups x 8 lanes, acc[16], 2-deep pipeline (measured best).
__global__ __launch_bounds__(256) void k_aggr(
    const int* __restrict__ esrc, const int* __restrict__ offsets, const int* __restrict__ degs,
    const unsigned short* __restrict__ hf16, const float* __restrict__ el, const float* __restrict__ er,
    float* __restrict__ out, float* __restrict__ mr, int N)
{
  __shared__ float as[4][64][4];
  __shared__ int   es[4][64];
  const int wave = threadIdx.x >> 6, lane = threadIdx.x & 63;
  const int v = blockIdx.x*4 + wave;
  if (v >= N) return;
  const int start = offsets[v];
  const int deg   = degs[v];
  const float4 er4 = *(const float4*)&er[(size_t)v*4];

  const bool act = lane < deg;
  float4 x4 = make_float4(0.f, 0.f, 0.f, 0.f);
  int mys = 0;
  if (act) {
    mys = esrc[start + lane];
    float4 el4 = *(const float4*)&el[(size_t)mys*4];
    x4.x = __expf(leaky(el4.x + er4.x));
    x4.y = __expf(leaky(el4.y + er4.y));
    x4.z = __expf(leaky(el4.z + er4.z));
    x4.w = __expf(leaky(el4.w + er4.w));
  }
  float4 s4 = x4;
  for (int j = lane + 64; j < deg; j += 64) {   // deg>64: essentially never
    int s = esrc[start + j];
    float4 el4 = *(const float4*)&el[(size_t)s*4];
    s4.x += __expf(leaky(el4.x + er4.x));
    s4.y += __expf(leaky(el4.y + er4.y));
    s4.z += __expf(leaky(el4.z + er4.z));
    s4.w += __expf(leaky(el4.w + er4.w));
  }
  #pragma unroll
  for (int mm = 32; mm; mm >>= 1) {
    s4.x += __shfl_xor(s4.x, mm);
    s4.y += __shfl_xor(s4.y, mm);
    s4.z += __shfl_xor(s4.z, mm);
    s4.w += __shfl_xor(s4.w, mm);
  }
  const float4 r4 = make_float4(1.f/s4.x, 1.f/s4.y, 1.f/s4.z, 1.f/s4.w);

  if (act) {
    float4 a4 = make_float4(x4.x*r4.x, x4.y*r4.y, x4.z*r4.z, x4.w*r4.w);
    *(float4*)&as[wave][lane][0] = a4;
    es[wave][lane] = mys;
  }
  if (lane == 0) *(float4*)&mr[(size_t)v*4] = r4;   // c = r (no max shift)

  // ---- pass B: aggregate, 8 groups x 8 lanes, 2-deep pipelined (16 edges in flight) ----
  const int g = lane >> 3;      // edge slot 0..7
  const int l = lane & 7;       // feature sublane: feats 16l..16l+15
  const int head = l >> 1;
  float acc[16];
  #pragma unroll
  for (int k = 0; k < 16; ++k) acc[k] = 0.f;

  const int degL = deg < 64 ? deg : 64;
  {
    int je = g;
    int jec = je < degL ? je : 0;
    int sj = es[wave][jec];
    float a = je < degL ? as[wave][jec][head] : 0.f;
    const unsigned short* hp = &hf16[(size_t)sj*128 + 16*l];
    uint4 q0 = *(const uint4*)hp;
    uint4 q1 = *(const uint4*)(hp + 8);
    for (int j = 0; j < degL; j += 8) {
      int je2 = j + 8 + g;
      int jec2 = je2 < degL ? je2 : 0;
      int s2 = es[wave][jec2];
      float a2 = je2 < degL ? as[wave][jec2][head] : 0.f;
      const unsigned short* hp2 = &hf16[(size_t)s2*128 + 16*l];
      uint4 p0 = *(const uint4*)hp2;
      uint4 p1 = *(const uint4*)(hp2 + 8);
      acc[0]  += a*b2f_lo(q0.x); acc[1]  += a*b2f_hi(q0.x);
      acc[2]  += a*b2f_lo(q0.y); acc[3]  += a*b2f_hi(q0.y);
      acc[4]  += a*b2f_lo(q0.z); acc[5]  += a*b2f_hi(q0.z);
      acc[6]  += a*b2f_lo(q0.w); acc[7]  += a*b2f_hi(q0.w);
      acc[8]  += a*b2f_lo(q1.x); acc[9]  += a*b2f_hi(q1.x);
      acc[10] += a*b2f_lo(q1.y); acc[11] += a*b2f_hi(q1.y);
      acc[12] += a*b2f_lo(q1.z); acc[13] += a*b2f_hi(q1.z);
      acc[14] += a*b2f_lo(q1.w); acc[15] += a*b2f_hi(q1.w);
      q0 = p0; q1 = p1; a = a2;
    }
  }
  for (int j = 64; j < deg; j += 8) {   // deg>64: essentially never
    const int je = j + g;
    const bool valid = je < deg;
    int s = esrc[start + (valid ? je : 0)];
    float rh = sel4(r4, head), erh = sel4(er4, head);
    float a = __expf(leaky(el[(size_t)s*4 + head] + erh)) * rh;
    if (!valid) a = 0.f;
    const unsigned short* hp = &hf16[(size_t)s*128 + 16*l];
    uint4 q0 = *(const uint4*)hp;
    uint4 q1 = *(const uint4*)(hp + 8);
    acc[0]  += a*b2f_lo(q0.x); acc[1]  += a*b2f_hi(q0.x);
    acc[2]  += a*b2f_lo(q0.y); acc[3]  += a*b2f_hi(q0.y);
    acc[4]  += a*b2f_lo(q0.z); acc[5]  += a*b2f_hi(q0.z);
    acc[6]  += a*b2f_lo(q0.w); acc[7]  += a*b2f_hi(q0.w);
    acc[8]  += a*b2f_lo(q1.x); acc[9]  += a*b2f_hi(q1.x);
    acc[10] += a*b2f_lo(q1.y); acc[11] += a*b2f_hi(q1.y);
    acc[12] += a*b2f_lo(q1.z); acc[13] += a*b2f_hi(q1.z);
    acc[14] += a*b2f_lo(q1.w); acc[15] += a*b2f_hi(q1.w);
  }

  #pragma unroll
  for (int k = 0; k < 16; ++k) {
    acc[k] += __shfl_xor(acc[k], 8);
    acc[k] += __shfl_xor(acc[k], 16);
    acc[k] += __shfl_xor(acc[k], 32);
  }
  if (g == 0) {
    float* op = &out[(size_t)v*128 + 16*l];
    ntstore_f4(op,      acc[0],  acc[1],  acc[2],  acc[3]);
    ntstore_f4(op + 4,  acc[4],  acc[5],  acc[6],  acc[7]);
    ntstore_f4(op + 8,  acc[8],  acc[9],  acc[10], acc[11]);
    ntstore_f4(op + 12, acc[12], acc[13], acc[14], acc[15]);
  }
}

// ---------------- K3: coalesced attention output, 4 edges/thread ----------------
// a = exp(leaky(el+er)) * c   with c = 1/sum(exp)  (no max shift)
__global__ void k_attn(const int* __restrict__ src, const int* __restrict__ dst,
                       const float* __restrict__ el, const float* __restrict__ er,
                       const float* __restrict__ mr, float* __restrict__ a_out, int E) {
  int e0 = (blockIdx.x*256 + threadIdx.x)*4;
  if (e0 + 3 < E) {
    vi4 sv = ntload_i4(&src[e0]);
    vi4 dv = ntload_i4(&dst[e0]);
    #pragma unroll
    for (int k = 0; k < 4; ++k) {
      int s = (k==0)?sv.x:(k==1)?sv.y:(k==2)?sv.z:sv.w;
      int d = (k==0)?dv.x:(k==1)?dv.y:(k==2)?dv.z:dv.w;
      float4 el4 = *(const float4*)&el[(size_t)s*4];
      float4 er4 = *(const float4*)&er[(size_t)d*4];
      float4 c4  = *(const float4*)&mr[(size_t)d*4];
      ntstore_f4(&a_out[(size_t)(e0+k)*4],
                 __expf(leaky(el4.x + er4.x)) * c4.x,
                 __expf(leaky(el4.y + er4.y)) * c4.y,
                 __expf(leaky(el4.z + er4.z)) * c4.z,
                 __expf(leaky(el4.w + er4.w)) * c4.w);
    }
  } else {
    for (int e = e0; e < E; ++e) {
      int s = src[e], d = dst[e];
      float4 el4 = *(const float4*)&el[(size_t)s*4];
      float4 er4 = *(const float4*)&er[(size_t)d*4];
      float4 c4  = *(const float4*)&mr[(size_t)d*4];
      ntstore_f4(&a_out[(size_t)e*4],
                 __expf(leaky(el4.x + er4.x)) * c4.x,
                 __expf(leaky(el4.y + er4.y)) * c4.y,
                 __expf(leaky(el4.z + er4.z)) * c4.z,
                 __expf(leaky(el4.w + er4.w)) * c4.w);
    }
  }
}

extern "C" void kernel_launch(void* const* d_in, const int* in_sizes, int n_in,
                              void* d_out, int out_size, void* d_ws, size_t ws_size,
                              hipStream_t stream) {
  const float* h      = (const float*)d_in[0];
  const float* fcw    = (const float*)d_in[1];
  const float* attn_l = (const float*)d_in[2];
  const float* attn_r = (const float*)d_in[3];
  const int*   src    = (const int*)d_in[4];
  const int*   dst    = (const int*)d_in[5];
  const int N = in_sizes[0] / 128;
  const int E = in_sizes[4];
  const int B = (N + 255) >> 8;    // buckets (assumes N <= 65536)

  float* out   = (float*)d_out;
  float* a_out = out + (size_t)N*128;

  char* w = (char*)d_ws;
  unsigned short* hf16 = (unsigned short*)w; w += (size_t)N*128*sizeof(unsigned short);
  float* el      = (float*)w; w += (size_t)N*4*sizeof(float);
  float* er      = (float*)w; w += (size_t)N*4*sizeof(float);
  float* mr      = (float*)w; w += (size_t)N*4*sizeof(float);
  int*   esrc    = (int*)w;   w += (size_t)256*BSTRIDE*sizeof(int);
  unsigned int* staging = (unsigned int*)w; w += (size_t)256*BSTRIDE*sizeof(unsigned int);
  int*   offsets = (int*)w;   w += (size_t)N*sizeof(int);
  int*   degs    = (int*)w;   w += (size_t)N*sizeof(int);
  int*   bcur    = (int*)w;   w += 256*sizeof(int);

  k_proj<<<(N + 127)/128, 256, 0, stream>>>(h, fcw, attn_l, attn_r, hf16, el, er, bcur, N);

  k_bin<<<(E + TILE - 1)/TILE, 1024, 0, stream>>>(src, dst, bcur, staging, E);
  k_debin<<<B, 1024, 0, stream>>>(staging, bcur, esrc, offsets, degs, N);

  k_aggr<<<(N + 3)/4, 256, 0, stream>>>(esrc, offsets, degs, hf16, el, er, out, mr, N);

  k_attn<<<(E/4 + 255)/256 + 1, 256, 0, stream>>>(src, dst, el, er, mr, a_out, E);
}

// Round 17
// 101.593 us; speedup vs baseline: 1.1444x; 1.0532x over previous
//
#include <hip/hip_runtime.h>
#include <hip/hip_bf16.h>

#define NEG 0.2f
#define BSTRIDE 8192   // padded per-bucket region (mean fill ~4350, 60-sigma headroom)

typedef float vf4 __attribute__((ext_vector_type(4)));
typedef int   vi4 __attribute__((ext_vector_type(4)));
typedef short bf8 __attribute__((ext_vector_type(8)));   // 8 bf16 (4 VGPRs)
typedef float f32x4 __attribute__((ext_vector_type(4)));

__device__ __forceinline__ float leaky(float x){ return x > 0.f ? x : NEG*x; }
__device__ __forceinline__ float sel4(float4 q, int head){
  float lo = (head & 1) ? q.y : q.x;
  float hi = (head & 1) ? q.w : q.z;
  return (head & 2) ? hi : lo;
}
__device__ __forceinline__ float b2f_lo(unsigned u){ return __uint_as_float(u << 16); }
__device__ __forceinline__ float b2f_hi(unsigned u){ return __uint_as_float(u & 0xffff0000u); }
__device__ __forceinline__ float b2f(unsigned short u){ return __uint_as_float((unsigned)u << 16); }
__device__ __forceinline__ unsigned short f2b(float f){
  __hip_bfloat16 b = __float2bfloat16(f);
  return *(unsigned short*)&b;
}
__device__ __forceinline__ void ntstore_f4(float* p, float a, float b, float c, float d){
  vf4 v; v.x = a; v.y = b; v.z = c; v.w = d;
  __builtin_nontemporal_store(v, (vf4*)p);
}

// ---------------- K1: hf16 = bf16(h @ fcw^T) via MFMA, fused el/er ----------------
// 128 nodes/block (2 node-tiles per wave over one fcw LDS staging). Block 0 seeds bcur.
// er goes into the interleaved erc table (stride 8: er at +0..3, c at +4..7).
__global__ __launch_bounds__(256) void k_proj(
    const float* __restrict__ h, const float* __restrict__ fcw,
    const float* __restrict__ attn_l, const float* __restrict__ attn_r,
    unsigned short* __restrict__ hf16, float* __restrict__ el, float* __restrict__ erc,
    int* __restrict__ bcur, int N)
{
  __shared__ __align__(16) unsigned short fcs[128*128];   // 32 KB bf16, swizzled
  __shared__ __align__(16) unsigned short hs[4][16*128];  // 16 KB D staging

  const int tid = threadIdx.x;
  if (blockIdx.x == 0) bcur[tid] = tid * BSTRIDE;   // folded k_binit

  // stage fcw -> bf16 LDS; chunk (8 elems, 16B) swizzled by f&7
  for (int i = tid; i < 128*16; i += 256) {
    int f = i >> 4, ch = i & 15;
    const float* p = &fcw[(size_t)f*128 + ch*8];
    float4 w0 = *(const float4*)p;
    float4 w1 = *(const float4*)(p + 4);
    unsigned short* q = &fcs[f*128 + (ch ^ (f & 7))*8];
    q[0]=f2b(w0.x); q[1]=f2b(w0.y); q[2]=f2b(w0.z); q[3]=f2b(w0.w);
    q[4]=f2b(w1.x); q[5]=f2b(w1.y); q[6]=f2b(w1.z); q[7]=f2b(w1.w);
  }
  __syncthreads();

  const int wave = tid >> 6, lane = tid & 63;
  const int r = lane & 15, khi = lane >> 4;      // A row / B col ; k-group 0..3

  for (int nt = 0; nt < 2; ++nt) {
    const int nb0 = blockIdx.x*128 + nt*64 + wave*16;
    int gn_a = nb0 + r; if (gn_a >= N) gn_a = N-1;
    const float* hp = &h[(size_t)gn_a*128];

    // A-frags: k = ks*32 + khi*8 + j  (same k-permutation as B -> contraction invariant)
    bf8 afr[4];
    #pragma unroll
    for (int ks = 0; ks < 4; ++ks) {
      const float* p = hp + ks*32 + khi*8;
      float4 w0 = *(const float4*)p;
      float4 w1 = *(const float4*)(p + 4);
      bf8 a;
      a[0]=(short)f2b(w0.x); a[1]=(short)f2b(w0.y); a[2]=(short)f2b(w0.z); a[3]=(short)f2b(w0.w);
      a[4]=(short)f2b(w1.x); a[5]=(short)f2b(w1.y); a[6]=(short)f2b(w1.z); a[7]=(short)f2b(w1.w);
      afr[ks] = a;
    }

    f32x4 acc[8];
    #pragma unroll
    for (int ct = 0; ct < 8; ++ct) { acc[ct][0]=0.f; acc[ct][1]=0.f; acc[ct][2]=0.f; acc[ct][3]=0.f; }

    #pragma unroll
    for (int ct = 0; ct < 8; ++ct) {
      const int f = ct*16 + r;                   // B col = feat
      #pragma unroll
      for (int ks = 0; ks < 4; ++ks) {
        const int ch = (ks*4 + khi) ^ (f & 7);
        bf8 b = *(const bf8*)&fcs[f*128 + ch*8];
        acc[ct] = __builtin_amdgcn_mfma_f32_16x16x32_bf16(afr[ks], b, acc[ct], 0, 0, 0);
      }
    }

    // D -> LDS (bf16). D map: col=lane&15 (feat), row=khi*4+j (node)
    unsigned short* hw = &hs[wave][0];
    #pragma unroll
    for (int ct = 0; ct < 8; ++ct) {
      const int ftile = ct*16 + r;
      #pragma unroll
      for (int j = 0; j < 4; ++j)
        hw[(khi*4 + j)*128 + ftile] = f2b(acc[ct][j]);
    }

    // coalesced hf16 writeback (wave-local LDS, no barrier needed)
    for (int i = lane; i < 16*16; i += 64) {
      int row = i >> 4, ch = i & 15;
      int gn = nb0 + row;
      if (gn < N)
        *(uint4*)&hf16[(size_t)gn*128 + ch*8] = *(const uint4*)&hw[row*128 + ch*8];
    }

    // el/er: lane = (node row, head); 32-MAC dot from LDS tile
    {
      const int row = lane >> 2, head = lane & 3;
      const int gn = nb0 + row;
      const unsigned short* hr = &hw[row*128 + head*32];
      const float* alp = &attn_l[head*32];
      const float* arp = &attn_r[head*32];
      float e_l = 0.f, e_r = 0.f;
      #pragma unroll
      for (int ff = 0; ff < 32; ++ff) {
        float hv = b2f(hr[ff]);
        e_l += hv * alp[ff];
        e_r += hv * arp[ff];
      }
      if (gn < N) {
        el[(size_t)gn*4 + head]  = e_l;
        erc[(size_t)gn*8 + head] = e_r;
      }
    }
  }
}

// ---------------- pass 1: bin edges into padded bucket regions ----------------
// staging word: (dst&255)<<24 | src   (src < 2^24)
#define TILE 4096
__global__ __launch_bounds__(1024) void k_bin(
    const int* __restrict__ src, const int* __restrict__ dst,
    int* __restrict__ bcur, unsigned int* __restrict__ staging, int E)
{
  __shared__ unsigned int lpack[TILE];
  __shared__ unsigned char lbkt[TILE];
  __shared__ unsigned short sidx[TILE];
  __shared__ int lhist[256], lbase[256], lcur[256], gbase[256];

  const int t = threadIdx.x;
  const int e0 = blockIdx.x * TILE;
  const int cnt = min(TILE, E - e0);

  if (t < 256) lhist[t] = 0;
  __syncthreads();

  for (int i = t; i < cnt; i += 1024) {
    int s = __builtin_nontemporal_load(&src[e0 + i]);
    int d = __builtin_nontemporal_load(&dst[e0 + i]);
    lpack[i] = ((unsigned)(d & 255) << 24) | (unsigned)s;
    int b = d >> 8;
    lbkt[i] = (unsigned char)b;
    atomicAdd(&lhist[b], 1);
  }
  __syncthreads();

  __shared__ int ltmp[256];
  if (t < 256) ltmp[t] = lhist[t];
  __syncthreads();
  for (int off = 1; off < 256; off <<= 1) {
    int x = 0;
    if (t < 256 && t >= off) x = ltmp[t - off];
    __syncthreads();
    if (t < 256) ltmp[t] += x;
    __syncthreads();
  }
  if (t < 256) { lbase[t] = ltmp[t] - lhist[t]; lcur[t] = ltmp[t] - lhist[t]; }
  __syncthreads();

  for (int i = t; i < cnt; i += 1024) {
    int p = atomicAdd(&lcur[lbkt[i]], 1);
    sidx[p] = (unsigned short)i;
  }
  if (t < 256) {
    int c = lhist[t];
    gbase[t] = c ? atomicAdd(&bcur[t], c) : 0;
  }
  __syncthreads();

  for (int p = t; p < cnt; p += 1024) {
    int j = sidx[p];
    int b = lbkt[j];
    staging[gbase[b] + (p - lbase[b])] = lpack[j];
  }
}

// ---------------- pass 2: per-bucket counting sort -> padded esrc + offsets/degs ----
__global__ __launch_bounds__(1024) void k_debin(
    const unsigned int* __restrict__ staging, const int* __restrict__ bcur,
    int* __restrict__ esrc, int* __restrict__ offsets, int* __restrict__ degs, int N)
{
  __shared__ int lout[BSTRIDE];
  __shared__ int lhist[256], lexcl[256], lcur[256];

  const int t = threadIdx.x;
  const int b = blockIdx.x;
  const int n0 = b << 8;
  const int nb = min(256, N - n0);
  const int out_start = b * BSTRIDE;
  const int cnt = bcur[b] - out_start;

  if (t < 256) lhist[t] = 0;
  __syncthreads();

  for (int i = t; i < cnt; i += 1024)
    atomicAdd(&lhist[staging[out_start + i] >> 24], 1);
  __syncthreads();

  if (t < 256) lexcl[t] = lhist[t];
  __syncthreads();
  for (int off = 1; off < 256; off <<= 1) {
    int x = 0;
    if (t < 256 && t >= off) x = lexcl[t - off];
    __syncthreads();
    if (t < 256) lexcl[t] += x;
    __syncthreads();
  }
  if (t < 256) {
    int ex = lexcl[t] - lhist[t];
    lexcl[t] = ex;
    lcur[t]  = ex;
  }
  __syncthreads();

  for (int i = t; i < cnt; i += 1024) {
    unsigned int w = staging[out_start + i];
    int p = atomicAdd(&lcur[w >> 24], 1);
    lout[p] = (int)(w & 0x00FFFFFFu);
  }
  __syncthreads();
  for (int i = t; i < cnt; i += 1024)
    esrc[out_start + i] = lout[i];

  if (t < nb) {
    offsets[n0 + t] = out_start + lexcl[t];
    degs[n0 + t]    = lhist[t];
  }
}

// ---------------- K2: per-dst softmax + aggregation (1 wave per node) ----------------
// Softmax WITHOUT max-shift: scores bounded, fp32 exp safe, shift-invariant.
// pass B: 8 edge groups x 8 lanes, acc[16], 2-deep pipeline (measured best).
// Publishes c = 1/sum into erc[v*8+4..7] (interleaved with er for k_attn's 1-line gather).
__global__ __launch_bounds__(256) void k_aggr(
    const int* __restrict__ esrc, const int* __restrict__ offsets, const int* __restrict__ degs,
    const unsigned short* __restrict__ hf16, const float* __restrict__ el, float* __restrict__ erc,
    float* __restrict__ out, int N)
{
  __shared__ float as[4][64][4];
  __shared__ int   es[4][64];
  const int wave = threadIdx.x >> 6, lane = threadIdx.x & 63;
  const int v = blockIdx.x*4 + wave;
  if (v >= N) return;
  const int start = offsets[v];
  const int deg   = degs[v];
  const float4 er4 = *(const float4*)&erc[(size_t)v*8];

  const bool act = lane < deg;
  float4 x4 = make_float4(0.f, 0.f, 0.f, 0.f);
  int mys = 0;
  if (act) {
    mys = esrc[start + lane];
    float4 el4 = *(const float4*)&el[(size_t)mys*4];
    x4.x = __expf(leaky(el4.x + er4.x));
    x4.y = __expf(leaky(el4.y + er4.y));
    x4.z = __expf(leaky(el4.z + er4.z));
    x4.w = __expf(leaky(el4.w + er4.w));
  }
  float4 s4 = x4;
  for (int j = lane + 64; j < deg; j += 64) {   // deg>64: essentially never
    int s = esrc[start + j];
    float4 el4 = *(const float4*)&el[(size_t)s*4];
    s4.x += __expf(leaky(el4.x + er4.x));
    s4.y += __expf(leaky(el4.y + er4.y));
    s4.z += __expf(leaky(el4.z + er4.z));
    s4.w += __expf(leaky(el4.w + er4.w));
  }
  #pragma unroll
  for (int mm = 32; mm; mm >>= 1) {
    s4.x += __shfl_xor(s4.x, mm);
    s4.y += __shfl_xor(s4.y, mm);
    s4.z += __shfl_xor(s4.z, mm);
    s4.w += __shfl_xor(s4.w, mm);
  }
  const float4 r4 = make_float4(1.f/s4.x, 1.f/s4.y, 1.f/s4.z, 1.f/s4.w);

  if (act) {
    float4 a4 = make_float4(x4.x*r4.x, x4.y*r4.y, x4.z*r4.z, x4.w*r4.w);
    *(float4*)&as[wave][lane][0] = a4;
    es[wave][lane] = mys;
  }
  if (lane == 0) *(float4*)&erc[(size_t)v*8 + 4] = r4;   // c = r (no max shift)

  // ---- pass B: aggregate, 8 groups x 8 lanes, 2-deep pipelined (16 edges in flight) ----
  const int g = lane >> 3;      // edge slot 0..7
  const int l = lane & 7;       // feature sublane: feats 16l..16l+15
  const int head = l >> 1;
  float acc[16];
  #pragma unroll
  for (int k = 0; k < 16; ++k) acc[k] = 0.f;

  const int degL = deg < 64 ? deg : 64;
  {
    int je = g;
    int jec = je < degL ? je : 0;
    int sj = es[wave][jec];
    float a = je < degL ? as[wave][jec][head] : 0.f;
    const unsigned short* hp = &hf16[(size_t)sj*128 + 16*l];
    uint4 q0 = *(const uint4*)hp;
    uint4 q1 = *(const uint4*)(hp + 8);
    for (int j = 0; j < degL; j += 8) {
      int je2 = j + 8 + g;
      int jec2 = je2 < degL ? je2 : 0;
      int s2 = es[wave][jec2];
      float a2 = je2 < degL ? as[wave][jec2][head] : 0.f;
      const unsigned short* hp2 = &hf16[(size_t)s2*128 + 16*l];
      uint4 p0 = *(const uint4*)hp2;
      uint4 p1 = *(const uint4*)(hp2 + 8);
      acc[0]  += a*b2f_lo(q0.x); acc[1]  += a*b2f_hi(q0.x);
      acc[2]  += a*b2f_lo(q0.y); acc[3]  += a*b2f_hi(q0.y);
      acc[4]  += a*b2f_lo(q0.z); acc[5]  += a*b2f_hi(q0.z);
      acc[6]  += a*b2f_lo(q0.w); acc[7]  += a*b2f_hi(q0.w);
      acc[8]  += a*b2f_lo(q1.x); acc[9]  += a*b2f_hi(q1.x);
      acc[10] += a*b2f_lo(q1.y); acc[11] += a*b2f_hi(q1.y);
      acc[12] += a*b2f_lo(q1.z); acc[13] += a*b2f_hi(q1.z);
      acc[14] += a*b2f_lo(q1.w); acc[15] += a*b2f_hi(q1.w);
      q0 = p0; q1 = p1; a = a2;
    }
  }
  for (int j = 64; j < deg; j += 8) {   // deg>64: essentially never
    const int je = j + g;
    const bool valid = je < deg;
    int s = esrc[start + (valid ? je : 0)];
    float rh = sel4(r4, head), erh = sel4(er4, head);
    float a = __expf(leaky(el[(size_t)s*4 + head] + erh)) * rh;
    if (!valid) a = 0.f;
    const unsigned short* hp = &hf16[(size_t)s*128 + 16*l];
    uint4 q0 = *(const uint4*)hp;
    uint4 q1 = *(const uint4*)(hp + 8);
    acc[0]  += a*b2f_lo(q0.x); acc[1]  += a*b2f_hi(q0.x);
    acc[2]  += a*b2f_lo(q0.y); acc[3]  += a*b2f_hi(q0.y);
    acc[4]  += a*b2f_lo(q0.z); acc[5]  += a*b2f_hi(q0.z);
    acc[6]  += a*b2f_lo(q0.w); acc[7]  += a*b2f_hi(q0.w);
    acc[8]  += a*b2f_lo(q1.x); acc[9]  += a*b2f_hi(q1.x);
    acc[10] += a*b2f_lo(q1.y); acc[11] += a*b2f_hi(q1.y);
    acc[12] += a*b2f_lo(q1.z); acc[13] += a*b2f_hi(q1.z);
    acc[14] += a*b2f_lo(q1.w); acc[15] += a*b2f_hi(q1.w);
  }

  #pragma unroll
  for (int k = 0; k < 16; ++k) {
    acc[k] += __shfl_xor(acc[k], 8);
    acc[k] += __shfl_xor(acc[k], 16);
    acc[k] += __shfl_xor(acc[k], 32);
  }
  if (g == 0) {
    float* op = &out[(size_t)v*128 + 16*l];
    ntstore_f4(op,      acc[0],  acc[1],  acc[2],  acc[3]);
    ntstore_f4(op + 4,  acc[4],  acc[5],  acc[6],  acc[7]);
    ntstore_f4(op + 8,  acc[8],  acc[9],  acc[10], acc[11]);
    ntstore_f4(op + 12, acc[12], acc[13], acc[14], acc[15]);
  }
}

// ---------------- K3: coalesced attention output (original edge order) ----------------
// a = exp(leaky(el+er)) * c ; er and c in ONE 32B region (single line fetch per dst).
__global__ void k_attn(const int* __restrict__ src, const int* __restrict__ dst,
                       const float* __restrict__ el, const float* __restrict__ erc,
                       float* __restrict__ a_out, int E) {
  int e = blockIdx.x*256 + threadIdx.x;
  if (e >= E) return;
  int s = __builtin_nontemporal_load(&src[e]);
  int d = __builtin_nontemporal_load(&dst[e]);
  float4 el4 = *(const float4*)&el[(size_t)s*4];
  float4 er4 = *(const float4*)&erc[(size_t)d*8];
  float4 c4  = *(const float4*)&erc[(size_t)d*8 + 4];
  float ax = __expf(leaky(el4.x + er4.x)) * c4.x;
  float ay = __expf(leaky(el4.y + er4.y)) * c4.y;
  float az = __expf(leaky(el4.z + er4.z)) * c4.z;
  float aw = __expf(leaky(el4.w + er4.w)) * c4.w;
  ntstore_f4(&a_out[(size_t)e*4], ax, ay, az, aw);
}

extern "C" void kernel_launch(void* const* d_in, const int* in_sizes, int n_in,
                              void* d_out, int out_size, void* d_ws, size_t ws_size,
                              hipStream_t stream) {
  const float* h      = (const float*)d_in[0];
  const float* fcw    = (const float*)d_in[1];
  const float* attn_l = (const float*)d_in[2];
  const float* attn_r = (const float*)d_in[3];
  const int*   src    = (const int*)d_in[4];
  const int*   dst    = (const int*)d_in[5];
  const int N = in_sizes[0] / 128;
  const int E = in_sizes[4];
  const int B = (N + 255) >> 8;    // buckets (assumes N <= 65536)

  float* out   = (float*)d_out;
  float* a_out = out + (size_t)N*128;

  char* w = (char*)d_ws;
  unsigned short* hf16 = (unsigned short*)w; w += (size_t)N*128*sizeof(unsigned short);
  float* el      = (float*)w; w += (size_t)N*4*sizeof(float);
  float* erc     = (float*)w; w += (size_t)N*8*sizeof(float);
  int*   esrc    = (int*)w;   w += (size_t)256*BSTRIDE*sizeof(int);
  unsigned int* staging = (unsigned int*)w; w += (size_t)256*BSTRIDE*sizeof(unsigned int);
  int*   offsets = (int*)w;   w += (size_t)N*sizeof(int);
  int*   degs    = (int*)w;   w += (size_t)N*sizeof(int);
  int*   bcur    = (int*)w;   w += 256*sizeof(int);

  k_proj<<<(N + 127)/128, 256, 0, stream>>>(h, fcw, attn_l, attn_r, hf16, el, erc, bcur, N);

  k_bin<<<(E + TILE - 1)/TILE, 1024, 0, stream>>>(src, dst, bcur, staging, E);
  k_debin<<<B, 1024, 0, stream>>>(staging, bcur, esrc, offsets, degs, N);

  k_aggr<<<(N + 3)/4, 256, 0, stream>>>(esrc, offsets, degs, hf16, el, erc, out, N);

  k_attn<<<(E + 255)/256, 256, 0, stream>>>(src, dst, el, erc, a_out, E);
}